// Round 3
// 740.578 us; speedup vs baseline: 1.3647x; 1.3647x over previous
//
#include <hip/hip_runtime.h>

#define B_   8
#define C_   512
#define H_   96
#define W_   96
#define HW_  (H_*W_)
#define NPIX_ (B_*HW_)

typedef unsigned short u16;
typedef __attribute__((ext_vector_type(8))) short short8;   // 8 bf16 = 4 VGPRs (MFMA A/B frag)
typedef __attribute__((ext_vector_type(4))) float f32x4;    // MFMA C/D frag
typedef __attribute__((address_space(1))) void as1_void;
typedef __attribute__((address_space(3))) void as3_void;

__device__ __forceinline__ float bf2f(u16 u) {
  unsigned int x = ((unsigned int)u) << 16;
  return __uint_as_float(x);
}
__device__ __forceinline__ u16 f2bf(float f) {
  unsigned int x = __float_as_uint(f);
  x += 0x7fffu + ((x >> 16) & 1u);   // RNE
  return (u16)(x >> 16);
}

// async global->LDS, 16 B per lane; LDS dest = wave-uniform base + lane*16
__device__ __forceinline__ void gld16(const void* g, void* l) {
  __builtin_amdgcn_global_load_lds((as1_void*)(const_cast<void*>(g)),
                                   (as3_void*)(l), 16, 0, 0);
}

// ---------------- prepass: x [b][c][hw] fp32 -> xT [b][pix][512] bf16
__global__ __launch_bounds__(256) void transpose_kernel(
    const float* __restrict__ x, u16* __restrict__ xT)
{
  const int p0 = blockIdx.x * 64, c0 = blockIdx.y * 64, b = blockIdx.z;
  __shared__ float tile[64*65];
  const int t = threadIdx.x;
  {
    const int cc = t >> 2, ps = (t & 3) * 16;
    const float* src = x + ((size_t)b*C_ + c0 + cc)*HW_ + p0 + ps;
    float4 f0 = *(const float4*)(src);
    float4 f1 = *(const float4*)(src + 4);
    float4 f2 = *(const float4*)(src + 8);
    float4 f3 = *(const float4*)(src + 12);
    float* d = tile + cc*65 + ps;
    d[0]=f0.x; d[1]=f0.y; d[2]=f0.z;  d[3]=f0.w;
    d[4]=f1.x; d[5]=f1.y; d[6]=f1.z;  d[7]=f1.w;
    d[8]=f2.x; d[9]=f2.y; d[10]=f2.z; d[11]=f2.w;
    d[12]=f3.x; d[13]=f3.y; d[14]=f3.z; d[15]=f3.w;
  }
  __syncthreads();
#pragma unroll
  for (int pass = 0; pass < 2; ++pass) {
    const int pr = pass*32 + (t >> 3), cs = (t & 7) * 8;
    union { u16 s[8]; uint4 v; } tmp;
#pragma unroll
    for (int i = 0; i < 8; ++i) tmp.s[i] = f2bf(tile[(cs + i)*65 + pr]);
    *(uint4*)(xT + ((size_t)b*HW_ + p0 + pr)*C_ + c0 + cs) = tmp.v;
  }
}

// ---------------- prepass: weights fp32 -> bf16.
// wdst layout (elems): [Wq 32768 | Wk 32768 | Wv 262144] = 327,680 elems
__global__ __launch_bounds__(256) void wconv_kernel(
    const float* __restrict__ Wq, const float* __restrict__ Wk,
    const float* __restrict__ Wv, u16* __restrict__ wdst)
{
  const int i = (blockIdx.x * 256 + threadIdx.x) * 4;
  const float* src; int off;
  if (i < 32768)      { src = Wq; off = 0; }
  else if (i < 65536) { src = Wk; off = 32768; }
  else                { src = Wv; off = 65536; }
  float4 f = *(const float4*)(src + (i - off));
  union { u16 s[4]; uint2 v; } o;
  o.s[0] = f2bf(f.x); o.s[1] = f2bf(f.y); o.s[2] = f2bf(f.z); o.s[3] = f2bf(f.w);
  *(uint2*)(wdst + i) = o.v;
}

__global__ __launch_bounds__(256) void wcopy_kernel(
    const uint4* __restrict__ s, uint4* __restrict__ d)
{
  const int i = blockIdx.x * 256 + threadIdx.x;
  d[i] = s[i];
}

// ---------------- MFMA projection GEMM:
// out[b][pix][ch] (bf16) = sum_c xT[b][pix][c]*Wt[ch][c] + bias[ch]
// grid (HW/128, NCH/128, nb), 256 threads = 4 waves, tile 128x128, BK=32
__global__ __launch_bounds__(256) void mfma_proj(
    const u16* __restrict__ xT, const u16* __restrict__ Wt,
    const float* __restrict__ bias0, const float* __restrict__ bias1,
    int split, int NCH, int b0, u16* __restrict__ outp)
{
  __shared__ __align__(16) u16 As[128*32];   // [pix][32k], rows 64 B, k-quads XOR-swizzled
  __shared__ __align__(16) u16 Bs[128*32];   // [ch][32k]
  const int b  = b0 + blockIdx.z;
  const int p0 = blockIdx.x * 128;
  const int n0 = blockIdx.y * 128;
  const int t = threadIdx.x;
  const int wv = t >> 6, lane = t & 63;
  const int wr = wv >> 1, wc = wv & 1;       // wave's 64x64 quadrant
  const int lhi = lane >> 4, llo = lane & 15;

  // staging: lane covers row = chunk*16 + (lane>>2), k-quad = (lane&3)^(row&3)
  const int srow = lane >> 2;
  const int skq  = (lane & 3) ^ (srow & 3);
  const u16* aG = xT + ((size_t)b*HW_ + p0 + srow) * C_ + skq * 8;
  const u16* bG = Wt + ((size_t)(n0 + srow)) * C_ + skq * 8;

  // frag read offsets (elems): quad q of row R sits at position q^(R&3)
  const int swz = (lhi ^ (llo & 3)) * 8;
  int aOff[4], bOff[4];
#pragma unroll
  for (int i = 0; i < 4; ++i) aOff[i] = (wr*64 + i*16 + llo)*32 + swz;
#pragma unroll
  for (int j = 0; j < 4; ++j) bOff[j] = (wc*64 + j*16 + llo)*32 + swz;

  f32x4 acc[4][4];
#pragma unroll
  for (int i = 0; i < 4; ++i)
#pragma unroll
    for (int j = 0; j < 4; ++j) acc[i][j] = (f32x4){0.f, 0.f, 0.f, 0.f};

  for (int k0 = 0; k0 < C_; k0 += 32) {
#pragma unroll
    for (int i = 0; i < 2; ++i) {
      const int chunk = wv*2 + i;            // wave-uniform
      gld16(aG + (size_t)chunk*16*C_ + k0, (void*)(As + chunk*512));
      gld16(bG + (size_t)chunk*16*C_ + k0, (void*)(Bs + chunk*512));
    }
    __syncthreads();                         // drains vmcnt before barrier
    short8 af[4], bfr[4];
#pragma unroll
    for (int i = 0; i < 4; ++i) af[i]  = *(const short8*)(As + aOff[i]);
#pragma unroll
    for (int j = 0; j < 4; ++j) bfr[j] = *(const short8*)(Bs + bOff[j]);
#pragma unroll
    for (int i = 0; i < 4; ++i)
#pragma unroll
      for (int j = 0; j < 4; ++j)
        acc[i][j] = __builtin_amdgcn_mfma_f32_16x16x32_bf16(af[i], bfr[j], acc[i][j], 0, 0, 0);
    __syncthreads();
  }

  // epilogue: D row (pix) = quad*4+reg, col (ch) = lane&15
#pragma unroll
  for (int j = 0; j < 4; ++j) {
    const int ch = n0 + wc*64 + j*16 + llo;
    const float bias = (ch < split) ? bias0[ch] : bias1[ch - split];
#pragma unroll
    for (int i = 0; i < 4; ++i) {
      const int pr = p0 + wr*64 + i*16 + lhi*4;
      u16* dst = outp + ((size_t)b*HW_ + pr) * NCH + ch;
#pragma unroll
      for (int r = 0; r < 4; ++r)
        dst[(size_t)r * NCH] = f2bf(acc[i][j][r] + bias);
    }
  }
}

// ---------------- eH logits: block per (w, b). qk bf16 [pix][128]: q=ch 0..63, k=ch 64..127
__global__ __launch_bounds__(256) void score_col_kernel(
    const u16* __restrict__ qk, float* __restrict__ att)
{
  const int w = blockIdx.x, b = blockIdx.y;
  __shared__ float qs[96*68];
  __shared__ float ks[96*68];
  const int t = threadIdx.x;
  for (int r = 0; r < 6; ++r) {
    int f = r*256 + t;                   // 1536 uint4 chunks
    int p = f >> 4, c8 = (f & 15) * 8;
    uint4 u = *(const uint4*)(qk + ((size_t)(b*HW_ + p*W_ + w))*128 + c8);
    float d[8];
    d[0]=bf2f(u.x & 0xffff); d[1]=bf2f(u.x >> 16);
    d[2]=bf2f(u.y & 0xffff); d[3]=bf2f(u.y >> 16);
    d[4]=bf2f(u.z & 0xffff); d[5]=bf2f(u.z >> 16);
    d[6]=bf2f(u.w & 0xffff); d[7]=bf2f(u.w >> 16);
    float* dst = (c8 < 64) ? (qs + p*68 + c8) : (ks + p*68 + (c8 - 64));
    *(float4*)(dst)     = make_float4(d[0], d[1], d[2], d[3]);
    *(float4*)(dst + 4) = make_float4(d[4], d[5], d[6], d[7]);
  }
  __syncthreads();
  const int ty = t >> 4, tx = t & 15;
  float e[6][6] = {};
#pragma unroll 8
  for (int c = 0; c < 64; ++c) {
    float qv[6], kv[6];
#pragma unroll
    for (int a = 0; a < 6; ++a) qv[a] = qs[(ty*6+a)*68 + c];
#pragma unroll
    for (int bb = 0; bb < 6; ++bb) kv[bb] = ks[(tx*6+bb)*68 + c];
#pragma unroll
    for (int a = 0; a < 6; ++a)
#pragma unroll
      for (int bb = 0; bb < 6; ++bb)
        e[a][bb] = fmaf(qv[a], kv[bb], e[a][bb]);
  }
#pragma unroll
  for (int a = 0; a < 6; ++a) {
    int h = ty*6 + a;
    size_t base = ((size_t)(b*H_ + h)*W_ + w) * 192;
#pragma unroll
    for (int bb = 0; bb < 6; ++bb) {
      int p = tx*6 + bb;
      att[base + p] = (h == p) ? -INFINITY : e[a][bb];
    }
  }
}

// ---------------- eW logits: block per (h, b)
__global__ __launch_bounds__(256) void score_row_kernel(
    const u16* __restrict__ qk, float* __restrict__ att)
{
  const int h = blockIdx.x, b = blockIdx.y;
  __shared__ float qs[96*68];
  __shared__ float ks[96*68];
  const int t = threadIdx.x;
  for (int r = 0; r < 6; ++r) {
    int f = r*256 + t;
    int p = f >> 4, c8 = (f & 15) * 8;
    uint4 u = *(const uint4*)(qk + ((size_t)(b*HW_ + h*W_ + p))*128 + c8);
    float d[8];
    d[0]=bf2f(u.x & 0xffff); d[1]=bf2f(u.x >> 16);
    d[2]=bf2f(u.y & 0xffff); d[3]=bf2f(u.y >> 16);
    d[4]=bf2f(u.z & 0xffff); d[5]=bf2f(u.z >> 16);
    d[6]=bf2f(u.w & 0xffff); d[7]=bf2f(u.w >> 16);
    float* dst = (c8 < 64) ? (qs + p*68 + c8) : (ks + p*68 + (c8 - 64));
    *(float4*)(dst)     = make_float4(d[0], d[1], d[2], d[3]);
    *(float4*)(dst + 4) = make_float4(d[4], d[5], d[6], d[7]);
  }
  __syncthreads();
  const int ty = t >> 4, tx = t & 15;
  float e[6][6] = {};
#pragma unroll 8
  for (int c = 0; c < 64; ++c) {
    float qv[6], kv[6];
#pragma unroll
    for (int a = 0; a < 6; ++a) qv[a] = qs[(ty*6+a)*68 + c];
#pragma unroll
    for (int bb = 0; bb < 6; ++bb) kv[bb] = ks[(tx*6+bb)*68 + c];
#pragma unroll
    for (int a = 0; a < 6; ++a)
#pragma unroll
      for (int bb = 0; bb < 6; ++bb)
        e[a][bb] = fmaf(qv[a], kv[bb], e[a][bb]);
  }
#pragma unroll
  for (int a = 0; a < 6; ++a) {
    int w = ty*6 + a;
    size_t base = ((size_t)(b*H_ + h)*W_ + w) * 192 + 96;
#pragma unroll
    for (int bb = 0; bb < 6; ++bb)
      att[base + tx*6 + bb] = e[a][bb];
  }
}

// ---------------- softmax over 192 logits per pixel; one wave per pixel
__global__ __launch_bounds__(256) void softmax_kernel(float* __restrict__ att)
{
  const int lane = threadIdx.x & 63;
  const int wv   = threadIdx.x >> 6;
  const size_t pix = (size_t)blockIdx.x * 4 + wv;
  float* row = att + pix * 192;
  float v0 = row[lane], v1 = row[lane+64], v2 = row[lane+128];
  float m = fmaxf(v0, fmaxf(v1, v2));
#pragma unroll
  for (int off = 32; off > 0; off >>= 1) m = fmaxf(m, __shfl_xor(m, off, 64));
  float e0 = __expf(v0 - m), e1 = __expf(v1 - m), e2 = __expf(v2 - m);
  float s = e0 + e1 + e2;
#pragma unroll
  for (int off = 32; off > 0; off >>= 1) s += __shfl_xor(s, off, 64);
  float inv = __frcp_rn(s);
  row[lane]     = e0 * inv;
  row[lane+64]  = e1 * inv;
  row[lane+128] = e2 * inv;
}

// ---------------- outH: block per (w, b), one 128-ch tile (c0 arg).
// tmpo[b][w][h][cl] = sum_p attH[h,p]*v[c0+cl,p,w]   (fully coalesced store)
__global__ __launch_bounds__(256) void outH_kernel(
    const float* __restrict__ att, const u16* __restrict__ vp,
    int c0, float* __restrict__ tmpo)
{
  const int w = blockIdx.x, b = blockIdx.z;
  __shared__ float as_[96*100];  // [h][p]
  __shared__ float vs[16*128];   // [pp][c]
  const int t = threadIdx.x;
  const int ty = t >> 4, tx = t & 15;
  for (int r = 0; r < 9; ++r) {
    int f = r*256 + t;
    int h = f / 24, p4 = (f % 24) * 4;
    *(float4*)(as_ + h*100 + p4) =
        *(const float4*)(att + ((size_t)((b*H_ + h)*W_ + w)) * 192 + p4);
  }
  float acc[6][8] = {};
  for (int p0 = 0; p0 < 96; p0 += 16) {
    {
      int pp = t >> 4, c8 = (t & 15) * 8;
      uint4 u = *(const uint4*)(vp + ((size_t)(b*HW_ + (p0+pp)*W_ + w))*C_ + c0 + c8);
      float* d = vs + pp*128 + c8;
      d[0] = bf2f((u16)(u.x & 0xffff)); d[1] = bf2f((u16)(u.x >> 16));
      d[2] = bf2f((u16)(u.y & 0xffff)); d[3] = bf2f((u16)(u.y >> 16));
      d[4] = bf2f((u16)(u.z & 0xffff)); d[5] = bf2f((u16)(u.z >> 16));
      d[6] = bf2f((u16)(u.w & 0xffff)); d[7] = bf2f((u16)(u.w >> 16));
    }
    __syncthreads();
#pragma unroll
    for (int pp = 0; pp < 16; ++pp) {
      float av[6], vv[8];
#pragma unroll
      for (int a = 0; a < 6; ++a) av[a] = as_[(ty + 16*a)*100 + p0 + pp];
#pragma unroll
      for (int j = 0; j < 8; ++j) vv[j] = vs[pp*128 + tx + 16*j];
#pragma unroll
      for (int a = 0; a < 6; ++a)
#pragma unroll
        for (int j = 0; j < 8; ++j)
          acc[a][j] = fmaf(av[a], vv[j], acc[a][j]);
    }
    __syncthreads();
  }
  // coalesced store: c_local innermost (16 lanes x 4 B = 64 B contiguous)
#pragma unroll
  for (int a = 0; a < 6; ++a) {
    int h = ty + 16*a;
    float* dst = tmpo + (((size_t)b*W_ + w)*H_ + h)*128;
#pragma unroll
    for (int j = 0; j < 8; ++j)
      dst[tx + 16*j] = acc[a][j];
  }
}

// ---------------- outW + fuse outH tile + residual:
// out = gamma*(sum_p attW[w,p]*v[c,h,p] + tmpo[b][w][h][cl]) + x
__global__ __launch_bounds__(256) void outW_kernel(
    const float* __restrict__ att, const u16* __restrict__ vp,
    const float* __restrict__ tmpo, const float* __restrict__ x,
    const float* __restrict__ gammap, int c0, float* __restrict__ out)
{
  const int h = blockIdx.x, b = blockIdx.z;
  __shared__ float as_[96*100];  // [w][p]; reused as tmp-stage [16][132] in epilogue
  __shared__ float vs[16*128];   // [pp][c]
  const int t = threadIdx.x;
  const int ty = t >> 4, tx = t & 15;
  for (int r = 0; r < 9; ++r) {
    int f = r*256 + t;
    int wl = f / 24, p4 = (f % 24) * 4;
    *(float4*)(as_ + wl*100 + p4) =
        *(const float4*)(att + ((size_t)((b*H_ + h)*W_ + wl)) * 192 + 96 + p4);
  }
  float acc[8][6] = {};
  for (int p0 = 0; p0 < 96; p0 += 16) {
    {
      int pp = t >> 4, c8 = (t & 15) * 8;
      uint4 u = *(const uint4*)(vp + ((size_t)(b*HW_ + h*W_ + p0 + pp))*C_ + c0 + c8);
      float* d = vs + pp*128 + c8;
      d[0] = bf2f((u16)(u.x & 0xffff)); d[1] = bf2f((u16)(u.x >> 16));
      d[2] = bf2f((u16)(u.y & 0xffff)); d[3] = bf2f((u16)(u.y >> 16));
      d[4] = bf2f((u16)(u.z & 0xffff)); d[5] = bf2f((u16)(u.z >> 16));
      d[6] = bf2f((u16)(u.w & 0xffff)); d[7] = bf2f((u16)(u.w >> 16));
    }
    __syncthreads();
#pragma unroll
    for (int pp = 0; pp < 16; ++pp) {
      float vv[8], aw[6];
#pragma unroll
      for (int a = 0; a < 8; ++a) vv[a] = vs[pp*128 + ty + 16*a];
#pragma unroll
      for (int j = 0; j < 6; ++j) aw[j] = as_[(tx + 16*j)*100 + p0 + pp];
#pragma unroll
      for (int a = 0; a < 8; ++a)
#pragma unroll
        for (int j = 0; j < 6; ++j)
          acc[a][j] = fmaf(vv[a], aw[j], acc[a][j]);
    }
    __syncthreads();
  }
  // epilogue: per 16-w chunk, stage tmpo coalesced via LDS (overlay on as_),
  // then fused add + residual + single coalesced out write.
  const float g = gammap[0];
  float* ts = as_;                       // [16][132] per chunk (pad kills conflicts)
#pragma unroll
  for (int j = 0; j < 6; ++j) {
    {
      int wl = j*16 + ty;                // 16 w rows, 128 floats each, coalesced
      const float* src = tmpo + (((size_t)b*W_ + wl)*H_ + h)*128 + tx*8;
      float4 u0 = *(const float4*)(src);
      float4 u1 = *(const float4*)(src + 4);
      float* d = ts + ty*132 + tx*8;
      *(float4*)(d)     = u0;
      *(float4*)(d + 4) = u1;
    }
    __syncthreads();
#pragma unroll
    for (int a = 0; a < 8; ++a) {
      int c = c0 + ty + 16*a;
      size_t idx = ((size_t)(b*C_ + c)*H_ + h)*W_ + tx + 16*j;
      out[idx] = g*(acc[a][j] + ts[tx*132 + ty + 16*a]) + x[idx];
    }
    __syncthreads();
  }
}

extern "C" void kernel_launch(void* const* d_in, const int* in_sizes, int n_in,
                              void* d_out, int out_size, void* d_ws, size_t ws_size,
                              hipStream_t stream) {
  const float* x     = (const float*)d_in[0];
  const float* Wq    = (const float*)d_in[1];
  const float* bq    = (const float*)d_in[2];
  const float* Wk    = (const float*)d_in[3];
  const float* bk    = (const float*)d_in[4];
  const float* Wv    = (const float*)d_in[5];
  const float* bv    = (const float*)d_in[6];
  const float* gamma = (const float*)d_in[7];
  float* out = (float*)d_out;
  char* ws = (char*)d_ws;

  // ws layout (169,869,312 B total):
  //   region0 @0        : xT bf16 [B][HW][512] (75,497,472 B) -> reused as att fp32 (56,623,104 B)
  //   qk      @75497472 : bf16 [B][HW][128] (18,874,368 B); weights parked at its base pre-proj
  //   vp      @94371840 : bf16 [B][HW][512] (75,497,472 B)
  //   tmpo    @56623104 : fp32 [B][W][H][128] (37,748,736 B) — region0 tail + dead qk,
  //                       live only during the outH/outW stage (att occupies [0,56623104))
  u16*   xT    = (u16*)ws;
  float* att   = (float*)ws;
  u16*   qk    = (u16*)(ws + 75497472);
  u16*   vp    = (u16*)(ws + 94371840);
  u16*   wpark = qk;                       // [Wq 32768 | Wk 32768 | Wv 262144] bf16 = 655,360 B
  u16*   wvbf  = wpark + 65536;            // Wv starts after Wq|Wk (65,536 elems)
  u16*   wqk0  = (u16*)(ws + 75366400);    // Wqk relocation target: last 131,072 B of region0
  float* tmpo  = (float*)(ws + 56623104);

  dim3 blk(256);
  wconv_kernel<<<320, blk, 0, stream>>>(Wq, Wk, Wv, wpark);
  transpose_kernel<<<dim3(HW_/64, C_/64, B_), blk, 0, stream>>>(x, xT);
  // q,k fused proj for batches 1..7 (their qk region doesn't overlap parked weights)
  mfma_proj<<<dim3(HW_/128, 1, 7), blk, 0, stream>>>(xT, wpark, bq, bk, 64, 128, 1, qk);
  // v proj, all batches
  mfma_proj<<<dim3(HW_/128, 4, 8), blk, 0, stream>>>(xT, wvbf, bv, bv, 512, 512, 0, vp);
  // xT batch 7 tail now dead -> relocate Wqk there (131,072 B = 8192 uint4), then batch-0 qk proj
  wcopy_kernel<<<32, blk, 0, stream>>>((const uint4*)wpark, (uint4*)wqk0);
  mfma_proj<<<dim3(HW_/128, 1, 1), blk, 0, stream>>>(xT, wqk0, bq, bk, 64, 128, 0, qk);
  score_col_kernel<<<dim3(W_, B_), blk, 0, stream>>>(qk, att);
  score_row_kernel<<<dim3(H_, B_), blk, 0, stream>>>(qk, att);
  softmax_kernel<<<dim3(NPIX_/4), blk, 0, stream>>>(att);
  // out stage: 4 c-tiles; outH writes coalesced partials to tmpo, outW fuses + residual.
  for (int ct = 0; ct < 4; ++ct) {
    outH_kernel<<<dim3(W_, 1, B_), blk, 0, stream>>>(att, vp, ct*128, tmpo);
    outW_kernel<<<dim3(H_, 1, B_), blk, 0, stream>>>(att, vp, tmpo, x, gamma, ct*128, out);
  }
}

// Round 4
// 650.222 us; speedup vs baseline: 1.5543x; 1.1390x over previous
//
#include <hip/hip_runtime.h>

#define B_   8
#define C_   512
#define H_   96
#define W_   96
#define HW_  (H_*W_)
#define NPIX_ (B_*HW_)
#define TMPO_ELEMS 9437184   // one bf16 tile slot: B*W*H*128

typedef unsigned short u16;
typedef __attribute__((ext_vector_type(8))) short short8;   // 8 bf16 = 4 VGPRs (MFMA A/B frag)
typedef __attribute__((ext_vector_type(4))) float f32x4;    // MFMA C/D frag
typedef __attribute__((address_space(1))) void as1_void;
typedef __attribute__((address_space(3))) void as3_void;

__device__ __forceinline__ float bf2f(u16 u) {
  unsigned int x = ((unsigned int)u) << 16;
  return __uint_as_float(x);
}
__device__ __forceinline__ u16 f2bf(float f) {
  unsigned int x = __float_as_uint(f);
  x += 0x7fffu + ((x >> 16) & 1u);   // RNE
  return (u16)(x >> 16);
}

// async global->LDS, 16 B per lane; LDS dest = wave-uniform base + lane*16
__device__ __forceinline__ void gld16(const void* g, void* l) {
  __builtin_amdgcn_global_load_lds((as1_void*)(const_cast<void*>(g)),
                                   (as3_void*)(l), 16, 0, 0);
}

// ---------------- prepass: x [b][c][hw] fp32 -> xT [b][pix][512] bf16
__global__ __launch_bounds__(256) void transpose_kernel(
    const float* __restrict__ x, u16* __restrict__ xT)
{
  const int p0 = blockIdx.x * 64, c0 = blockIdx.y * 64, b = blockIdx.z;
  __shared__ float tile[64*65];
  const int t = threadIdx.x;
  {
    const int cc = t >> 2, ps = (t & 3) * 16;
    const float* src = x + ((size_t)b*C_ + c0 + cc)*HW_ + p0 + ps;
    float4 f0 = *(const float4*)(src);
    float4 f1 = *(const float4*)(src + 4);
    float4 f2 = *(const float4*)(src + 8);
    float4 f3 = *(const float4*)(src + 12);
    float* d = tile + cc*65 + ps;
    d[0]=f0.x; d[1]=f0.y; d[2]=f0.z;  d[3]=f0.w;
    d[4]=f1.x; d[5]=f1.y; d[6]=f1.z;  d[7]=f1.w;
    d[8]=f2.x; d[9]=f2.y; d[10]=f2.z; d[11]=f2.w;
    d[12]=f3.x; d[13]=f3.y; d[14]=f3.z; d[15]=f3.w;
  }
  __syncthreads();
#pragma unroll
  for (int pass = 0; pass < 2; ++pass) {
    const int pr = pass*32 + (t >> 3), cs = (t & 7) * 8;
    union { u16 s[8]; uint4 v; } tmp;
#pragma unroll
    for (int i = 0; i < 8; ++i) tmp.s[i] = f2bf(tile[(cs + i)*65 + pr]);
    *(uint4*)(xT + ((size_t)b*HW_ + p0 + pr)*C_ + c0 + cs) = tmp.v;
  }
}

// ---------------- prepass: weights fp32 -> bf16 parked in d_out (dead until outW).
// wdst layout (elems): [Wq 64rows | Wk 64rows | Wv 512rows] x 512 = 327,680 elems
__global__ __launch_bounds__(256) void wconv_kernel(
    const float* __restrict__ Wq, const float* __restrict__ Wk,
    const float* __restrict__ Wv, u16* __restrict__ wdst)
{
  const int i = (blockIdx.x * 256 + threadIdx.x) * 4;
  const float* src; int off;
  if (i < 32768)      { src = Wq; off = 0; }
  else if (i < 65536) { src = Wk; off = 32768; }
  else                { src = Wv; off = 65536; }
  float4 f = *(const float4*)(src + (i - off));
  union { u16 s[4]; uint2 v; } o;
  o.s[0] = f2bf(f.x); o.s[1] = f2bf(f.y); o.s[2] = f2bf(f.z); o.s[3] = f2bf(f.w);
  *(uint2*)(wdst + i) = o.v;
}

// ---------------- fused MFMA projection GEMM (q,k,v in one launch):
// grid (72, 5, 8). y=0 -> qk[b][pix][128]; y=1..4 -> vp[b][pix][512] tile (y-1)*128.
__global__ __launch_bounds__(256) void mfma_proj(
    const u16* __restrict__ xT, const u16* __restrict__ Wt,
    const float* __restrict__ bq, const float* __restrict__ bk,
    const float* __restrict__ bv, u16* __restrict__ qkp, u16* __restrict__ vpp)
{
  __shared__ __align__(16) u16 As[128*32];   // [pix][32k], rows 64 B, k-quads XOR-swizzled
  __shared__ __align__(16) u16 Bs[128*32];   // [ch][32k]
  const int b  = blockIdx.z;
  const int p0 = blockIdx.x * 128;
  const int n0 = blockIdx.y * 128;           // global weight row base (0..512)
  const int t = threadIdx.x;
  const int wv = t >> 6, lane = t & 63;
  const int wr = wv >> 1, wc = wv & 1;       // wave's 64x64 quadrant
  const int lhi = lane >> 4, llo = lane & 15;

  // staging: lane covers row = chunk*16 + (lane>>2), k-quad = (lane&3)^(row&3)
  const int srow = lane >> 2;
  const int skq  = (lane & 3) ^ (srow & 3);
  const u16* aG = xT + ((size_t)b*HW_ + p0 + srow) * C_ + skq * 8;
  const u16* bG = Wt + ((size_t)(n0 + srow)) * C_ + skq * 8;

  // frag read offsets (elems): quad q of row R sits at position q^(R&3)
  const int swz = (lhi ^ (llo & 3)) * 8;
  int aOff[4], bOff[4];
#pragma unroll
  for (int i = 0; i < 4; ++i) aOff[i] = (wr*64 + i*16 + llo)*32 + swz;
#pragma unroll
  for (int j = 0; j < 4; ++j) bOff[j] = (wc*64 + j*16 + llo)*32 + swz;

  f32x4 acc[4][4];
#pragma unroll
  for (int i = 0; i < 4; ++i)
#pragma unroll
    for (int j = 0; j < 4; ++j) acc[i][j] = (f32x4){0.f, 0.f, 0.f, 0.f};

  for (int k0 = 0; k0 < C_; k0 += 32) {
#pragma unroll
    for (int i = 0; i < 2; ++i) {
      const int chunk = wv*2 + i;            // wave-uniform
      gld16(aG + (size_t)chunk*16*C_ + k0, (void*)(As + chunk*512));
      gld16(bG + (size_t)chunk*16*C_ + k0, (void*)(Bs + chunk*512));
    }
    __syncthreads();                         // drains vmcnt before barrier
    short8 af[4], bfr[4];
#pragma unroll
    for (int i = 0; i < 4; ++i) af[i]  = *(const short8*)(As + aOff[i]);
#pragma unroll
    for (int j = 0; j < 4; ++j) bfr[j] = *(const short8*)(Bs + bOff[j]);
#pragma unroll
    for (int i = 0; i < 4; ++i)
#pragma unroll
      for (int j = 0; j < 4; ++j)
        acc[i][j] = __builtin_amdgcn_mfma_f32_16x16x32_bf16(af[i], bfr[j], acc[i][j], 0, 0, 0);
    __syncthreads();
  }

  // epilogue: D row (pix) = quad*4+reg, col = lane&15; route by blockIdx.y
  const bool isQK = (blockIdx.y == 0);
  u16* op = isQK ? qkp : vpp;
  const int NCH = isQK ? 128 : 512;
  const int chBase = isQK ? 0 : (n0 - 128);
#pragma unroll
  for (int j = 0; j < 4; ++j) {
    const int chl = wc*64 + j*16 + llo;      // 0..127 within tile
    const float bias = isQK ? ((chl < 64) ? bq[chl] : bk[chl - 64])
                            : bv[chBase + chl];
#pragma unroll
    for (int i = 0; i < 4; ++i) {
      const int pr = p0 + wr*64 + i*16 + lhi*4;
      u16* dst = op + ((size_t)b*HW_ + pr) * NCH + chBase + chl;
#pragma unroll
      for (int r = 0; r < 4; ++r)
        dst[(size_t)r * NCH] = f2bf(acc[i][j][r] + bias);
    }
  }
}

// ---------------- eH logits: block per (w, b). qk bf16 [pix][128]: q=ch 0..63, k=ch 64..127
// writes raw fp32 logits attL[b][h][w][96] (diag = -inf)
__global__ __launch_bounds__(256) void score_col_kernel(
    const u16* __restrict__ qk, float* __restrict__ attL)
{
  const int w = blockIdx.x, b = blockIdx.y;
  __shared__ float qs[96*68];
  __shared__ float ks[96*68];
  const int t = threadIdx.x;
  for (int r = 0; r < 6; ++r) {
    int f = r*256 + t;                   // 1536 uint4 chunks
    int p = f >> 4, c8 = (f & 15) * 8;
    uint4 u = *(const uint4*)(qk + ((size_t)(b*HW_ + p*W_ + w))*128 + c8);
    float d[8];
    d[0]=bf2f(u.x & 0xffff); d[1]=bf2f(u.x >> 16);
    d[2]=bf2f(u.y & 0xffff); d[3]=bf2f(u.y >> 16);
    d[4]=bf2f(u.z & 0xffff); d[5]=bf2f(u.z >> 16);
    d[6]=bf2f(u.w & 0xffff); d[7]=bf2f(u.w >> 16);
    float* dst = (c8 < 64) ? (qs + p*68 + c8) : (ks + p*68 + (c8 - 64));
    *(float4*)(dst)     = make_float4(d[0], d[1], d[2], d[3]);
    *(float4*)(dst + 4) = make_float4(d[4], d[5], d[6], d[7]);
  }
  __syncthreads();
  const int ty = t >> 4, tx = t & 15;
  float e[6][6] = {};
#pragma unroll 8
  for (int c = 0; c < 64; ++c) {
    float qv[6], kv[6];
#pragma unroll
    for (int a = 0; a < 6; ++a) qv[a] = qs[(ty*6+a)*68 + c];
#pragma unroll
    for (int bb = 0; bb < 6; ++bb) kv[bb] = ks[(tx*6+bb)*68 + c];
#pragma unroll
    for (int a = 0; a < 6; ++a)
#pragma unroll
      for (int bb = 0; bb < 6; ++bb)
        e[a][bb] = fmaf(qv[a], kv[bb], e[a][bb]);
  }
#pragma unroll
  for (int a = 0; a < 6; ++a) {
    int h = ty*6 + a;
    size_t base = ((size_t)((b*H_ + h)*W_ + w)) * 96;
#pragma unroll
    for (int bb = 0; bb < 6; ++bb) {
      int p = tx*6 + bb;
      attL[base + p] = (h == p) ? -INFINITY : e[a][bb];
    }
  }
}

// ---------------- eW logits + fused softmax: block per (h, b).
// Computes eW in-register, stages to LDS, combines with eH (attL, written by
// score_col which completed in stream order), softmax over 192, writes bf16
// attF[b][h][w][192] (attH | attW).
__global__ __launch_bounds__(256) void score_row_kernel(
    const u16* __restrict__ qk, const float* __restrict__ attL,
    u16* __restrict__ attF)
{
  const int h = blockIdx.x, b = blockIdx.y;
  __shared__ float smem[2*96*68];            // qs|ks; reused as esW[96][97]
  float* qs = smem;
  float* ks = smem + 96*68;
  const int t = threadIdx.x;
  for (int r = 0; r < 6; ++r) {
    int f = r*256 + t;
    int p = f >> 4, c8 = (f & 15) * 8;
    uint4 u = *(const uint4*)(qk + ((size_t)(b*HW_ + h*W_ + p))*128 + c8);
    float d[8];
    d[0]=bf2f(u.x & 0xffff); d[1]=bf2f(u.x >> 16);
    d[2]=bf2f(u.y & 0xffff); d[3]=bf2f(u.y >> 16);
    d[4]=bf2f(u.z & 0xffff); d[5]=bf2f(u.z >> 16);
    d[6]=bf2f(u.w & 0xffff); d[7]=bf2f(u.w >> 16);
    float* dst = (c8 < 64) ? (qs + p*68 + c8) : (ks + p*68 + (c8 - 64));
    *(float4*)(dst)     = make_float4(d[0], d[1], d[2], d[3]);
    *(float4*)(dst + 4) = make_float4(d[4], d[5], d[6], d[7]);
  }
  __syncthreads();
  const int ty = t >> 4, tx = t & 15;
  float e[6][6] = {};
#pragma unroll 8
  for (int c = 0; c < 64; ++c) {
    float qv[6], kv[6];
#pragma unroll
    for (int a = 0; a < 6; ++a) qv[a] = qs[(ty*6+a)*68 + c];
#pragma unroll
    for (int bb = 0; bb < 6; ++bb) kv[bb] = ks[(tx*6+bb)*68 + c];
#pragma unroll
    for (int a = 0; a < 6; ++a)
#pragma unroll
      for (int bb = 0; bb < 6; ++bb)
        e[a][bb] = fmaf(qv[a], kv[bb], e[a][bb]);
  }
  __syncthreads();                           // all qs/ks reads done
  float* esW = smem;                         // [96][97] (97: conflict-free col reads)
#pragma unroll
  for (int a = 0; a < 6; ++a)
#pragma unroll
    for (int bb = 0; bb < 6; ++bb)
      esW[(ty*6 + a)*97 + tx*6 + bb] = e[a][bb];
  __syncthreads();
  // fused softmax: 2 lanes per pixel (lane pair via shfl_xor 1)
  if (t < 192) {
    const int w = t >> 1, hf = t & 1;
    float v[96];
    if (hf == 0) {
      const float4* src = (const float4*)(attL + ((size_t)((b*H_ + h)*W_ + w)) * 96);
#pragma unroll
      for (int i = 0; i < 24; ++i) {
        float4 f4 = src[i];
        v[4*i]=f4.x; v[4*i+1]=f4.y; v[4*i+2]=f4.z; v[4*i+3]=f4.w;
      }
    } else {
      const float* src = esW + w*97;
#pragma unroll
      for (int i = 0; i < 96; ++i) v[i] = src[i];
    }
    float m = v[0];
#pragma unroll
    for (int i = 1; i < 96; ++i) m = fmaxf(m, v[i]);
    m = fmaxf(m, __shfl_xor(m, 1, 64));
    float s = 0.f;
#pragma unroll
    for (int i = 0; i < 96; ++i) { v[i] = __expf(v[i] - m); s += v[i]; }
    s += __shfl_xor(s, 1, 64);
    const float inv = __frcp_rn(s);
    u16* dst = attF + ((size_t)((b*H_ + h)*W_ + w)) * 192 + hf*96;
#pragma unroll
    for (int i = 0; i < 12; ++i) {
      union { u16 s4[8]; uint4 u; } o;
#pragma unroll
      for (int k = 0; k < 8; ++k) o.s4[k] = f2bf(v[i*8 + k] * inv);
      ((uint4*)dst)[i] = o.u;
    }
  }
}

// ---------------- outH: block per (w, ytile, b); c0 = cr0 + y*128, tmpo slot = y.
// tmpo[slot][b][w][h][cl] (bf16) = sum_p attH[h,p]*v[c0+cl,p,w]; lane owns 8 contiguous c.
__global__ __launch_bounds__(256) void outH_kernel(
    const u16* __restrict__ attF, const u16* __restrict__ vp,
    int cr0, u16* __restrict__ tmpo)
{
  const int w = blockIdx.x, b = blockIdx.z;
  const int c0 = cr0 + (int)blockIdx.y * 128;
  u16* tdst = tmpo + (size_t)blockIdx.y * TMPO_ELEMS;
  __shared__ float as_[96*100];  // [h][p] fp32
  __shared__ float vs[16*132];   // [pp][c] fp32
  const int t = threadIdx.x;
  const int ty = t >> 4, tx = t & 15;
  // stage attH (bf16 -> fp32): 96 rows x 12 uint4
  for (int r = 0; r < 5; ++r) {
    int f = r*256 + t;
    if (f < 1152) {
      int hh = f / 12, p8 = (f % 12) * 8;
      uint4 u = *(const uint4*)(attF + ((size_t)((b*H_ + hh)*W_ + w))*192 + p8);
      float* d = as_ + hh*100 + p8;
      d[0]=bf2f(u.x & 0xffff); d[1]=bf2f(u.x >> 16);
      d[2]=bf2f(u.y & 0xffff); d[3]=bf2f(u.y >> 16);
      d[4]=bf2f(u.z & 0xffff); d[5]=bf2f(u.z >> 16);
      d[6]=bf2f(u.w & 0xffff); d[7]=bf2f(u.w >> 16);
    }
  }
  float acc[6][8] = {};
  for (int p0 = 0; p0 < 96; p0 += 16) {
    {
      int pp = ty, c8 = tx * 8;
      uint4 u = *(const uint4*)(vp + ((size_t)(b*HW_ + (p0+pp)*W_ + w))*C_ + c0 + c8);
      float* d = vs + pp*132 + c8;
      d[0]=bf2f((u16)(u.x & 0xffff)); d[1]=bf2f((u16)(u.x >> 16));
      d[2]=bf2f((u16)(u.y & 0xffff)); d[3]=bf2f((u16)(u.y >> 16));
      d[4]=bf2f((u16)(u.z & 0xffff)); d[5]=bf2f((u16)(u.z >> 16));
      d[6]=bf2f((u16)(u.w & 0xffff)); d[7]=bf2f((u16)(u.w >> 16));
    }
    __syncthreads();
#pragma unroll
    for (int pp = 0; pp < 16; ++pp) {
      float av[6];
#pragma unroll
      for (int a = 0; a < 6; ++a) av[a] = as_[(ty + 16*a)*100 + p0 + pp];
      float4 v0 = *(const float4*)(vs + pp*132 + tx*8);
      float4 v1 = *(const float4*)(vs + pp*132 + tx*8 + 4);
      float vv[8] = {v0.x,v0.y,v0.z,v0.w, v1.x,v1.y,v1.z,v1.w};
#pragma unroll
      for (int a = 0; a < 6; ++a)
#pragma unroll
        for (int j = 0; j < 8; ++j)
          acc[a][j] = fmaf(av[a], vv[j], acc[a][j]);
    }
    __syncthreads();
  }
  // store bf16, lane owns c = tx*8..tx*8+7 (contiguous 16 B)
#pragma unroll
  for (int a = 0; a < 6; ++a) {
    int hh = ty + 16*a;
    union { u16 s4[8]; uint4 u; } o;
#pragma unroll
    for (int j = 0; j < 8; ++j) o.s4[j] = f2bf(acc[a][j]);
    *(uint4*)(tdst + (((size_t)b*W_ + w)*H_ + hh)*128 + tx*8) = o.u;
  }
}

// ---------------- outW + fuse outH tile + residual:
// out = gamma*(sum_p attW[w,p]*v[c,h,p] + tmpo) + x; lane owns 8 contiguous c.
__global__ __launch_bounds__(256) void outW_kernel(
    const u16* __restrict__ attF, const u16* __restrict__ vp,
    const u16* __restrict__ tmpo, const float* __restrict__ x,
    const float* __restrict__ gammap, int cr0, float* __restrict__ out)
{
  const int h = blockIdx.x, b = blockIdx.z;
  const int c0 = cr0 + (int)blockIdx.y * 128;
  const u16* tsrc = tmpo + (size_t)blockIdx.y * TMPO_ELEMS;
  __shared__ float as_[96*100];  // [w][p]; reused as ts[16][132] in epilogue
  __shared__ float vs[16*132];   // [pp][c]
  const int t = threadIdx.x;
  const int ty = t >> 4, tx = t & 15;
  // stage attW (bf16 -> fp32)
  for (int r = 0; r < 5; ++r) {
    int f = r*256 + t;
    if (f < 1152) {
      int wl = f / 12, p8 = (f % 12) * 8;
      uint4 u = *(const uint4*)(attF + ((size_t)((b*H_ + h)*W_ + wl))*192 + 96 + p8);
      float* d = as_ + wl*100 + p8;
      d[0]=bf2f(u.x & 0xffff); d[1]=bf2f(u.x >> 16);
      d[2]=bf2f(u.y & 0xffff); d[3]=bf2f(u.y >> 16);
      d[4]=bf2f(u.z & 0xffff); d[5]=bf2f(u.z >> 16);
      d[6]=bf2f(u.w & 0xffff); d[7]=bf2f(u.w >> 16);
    }
  }
  float acc[8][6] = {};
  for (int p0 = 0; p0 < 96; p0 += 16) {
    {
      int pp = ty, c8 = tx * 8;
      uint4 u = *(const uint4*)(vp + ((size_t)(b*HW_ + h*W_ + p0 + pp))*C_ + c0 + c8);
      float* d = vs + pp*132 + c8;
      d[0]=bf2f((u16)(u.x & 0xffff)); d[1]=bf2f((u16)(u.x >> 16));
      d[2]=bf2f((u16)(u.y & 0xffff)); d[3]=bf2f((u16)(u.y >> 16));
      d[4]=bf2f((u16)(u.z & 0xffff)); d[5]=bf2f((u16)(u.z >> 16));
      d[6]=bf2f((u16)(u.w & 0xffff)); d[7]=bf2f((u16)(u.w >> 16));
    }
    __syncthreads();
#pragma unroll
    for (int pp = 0; pp < 16; ++pp) {
      float aw[6];
#pragma unroll
      for (int j = 0; j < 6; ++j) aw[j] = as_[(tx + 16*j)*100 + p0 + pp];
      float4 v0 = *(const float4*)(vs + pp*132 + ty*8);
      float4 v1 = *(const float4*)(vs + pp*132 + ty*8 + 4);
      float vv[8] = {v0.x,v0.y,v0.z,v0.w, v1.x,v1.y,v1.z,v1.w};
#pragma unroll
      for (int a = 0; a < 8; ++a)
#pragma unroll
        for (int j = 0; j < 6; ++j)
          acc[a][j] = fmaf(vv[a], aw[j], acc[a][j]);
    }
    __syncthreads();
  }
  // epilogue: per 16-w chunk, stage tmpo (bf16) via LDS, fuse + residual.
  const float g = gammap[0];
  float* ts = as_;                       // [16][132]
#pragma unroll
  for (int j = 0; j < 6; ++j) {
    {
      int wl = j*16 + ty;                // 16 w rows x 128 bf16, coalesced
      uint4 u = *(const uint4*)(tsrc + (((size_t)b*W_ + wl)*H_ + h)*128 + tx*8);
      float* d = ts + ty*132 + tx*8;
      d[0]=bf2f((u16)(u.x & 0xffff)); d[1]=bf2f((u16)(u.x >> 16));
      d[2]=bf2f((u16)(u.y & 0xffff)); d[3]=bf2f((u16)(u.y >> 16));
      d[4]=bf2f((u16)(u.z & 0xffff)); d[5]=bf2f((u16)(u.z >> 16));
      d[6]=bf2f((u16)(u.w & 0xffff)); d[7]=bf2f((u16)(u.w >> 16));
    }
    __syncthreads();
#pragma unroll
    for (int a = 0; a < 8; ++a) {
      int c = c0 + ty*8 + a;
      size_t idx = ((size_t)(b*C_ + c)*H_ + h)*W_ + tx + 16*j;
      out[idx] = g*(acc[a][j] + ts[tx*132 + ty*8 + a]) + x[idx];
    }
    __syncthreads();
  }
}

extern "C" void kernel_launch(void* const* d_in, const int* in_sizes, int n_in,
                              void* d_out, int out_size, void* d_ws, size_t ws_size,
                              hipStream_t stream) {
  const float* x     = (const float*)d_in[0];
  const float* Wq    = (const float*)d_in[1];
  const float* bq    = (const float*)d_in[2];
  const float* Wk    = (const float*)d_in[3];
  const float* bk    = (const float*)d_in[4];
  const float* Wv    = (const float*)d_in[5];
  const float* bv    = (const float*)d_in[6];
  const float* gamma = (const float*)d_in[7];
  float* out = (float*)d_out;
  char* ws = (char*)d_ws;

  // ws layout (169,869,312 B):
  //   xT    @0        : bf16 [B][HW][512] (75,497,472 B), live through mfma_proj
  //   attF  @0        : bf16 [B][H][W][192] (28,311,552 B)  — overlays dead xT
  //   attL  @28311552 : fp32 [B][H][W][96]  (28,311,552 B)  — overlays dead xT
  //   tmpo  @56623104 : bf16 2 slots x [B][W][H][128] (2 x 18,874,368 B)
  //                     slot0 = dead xT tail, slot1 = dead qk region
  //   qk    @75497472 : bf16 [B][HW][128] (18,874,368 B)
  //   vp    @94371840 : bf16 [B][HW][512] (75,497,472 B)
  // weights: bf16 [640][512] (655,360 B) parked in d_out (dead until outW).
  u16*   xT   = (u16*)ws;
  u16*   attF = (u16*)ws;
  float* attL = (float*)(ws + 28311552);
  u16*   tmpo = (u16*)(ws + 56623104);
  u16*   qk   = (u16*)(ws + 75497472);
  u16*   vp   = (u16*)(ws + 94371840);
  u16*   wbf  = (u16*)d_out;

  dim3 blk(256);
  wconv_kernel<<<320, blk, 0, stream>>>(Wq, Wk, Wv, wbf);
  transpose_kernel<<<dim3(HW_/64, C_/64, B_), blk, 0, stream>>>(x, xT);
  mfma_proj<<<dim3(HW_/128, 5, B_), blk, 0, stream>>>(xT, wbf, bq, bk, bv, qk, vp);
  score_col_kernel<<<dim3(W_, B_), blk, 0, stream>>>(qk, attL);
  score_row_kernel<<<dim3(H_, B_), blk, 0, stream>>>(qk, attL, attF);
  for (int r = 0; r < 2; ++r) {
    outH_kernel<<<dim3(W_, 2, B_), blk, 0, stream>>>(attF, vp, r*256, tmpo);
    outW_kernel<<<dim3(H_, 2, B_), blk, 0, stream>>>(attF, vp, tmpo, x, gamma, r*256, out);
  }
}